// Round 13
// baseline (2630.538 us; speedup 1.0000x reference)
//
#include <hip/hip_runtime.h>
#include <math.h>

#define NB 256
#define NH 2048
#define ND 8
#define NI 16
#define NT 128
#define NO 4
#define KKT 33           // K chunks of 64: 32 rec + 1 ext (w_in + zero pad) -> K = 2112
#define NTHR 512
#define NBLK 256
#define DPF 6            // A-prefetch depth (register pipeline)

typedef __attribute__((ext_vector_type(4))) int i32x4;
typedef __attribute__((ext_vector_type(2))) long i64x2;

// ---- ws byte offsets ----
// W: [128 ht][33 kk][4 sp][64 lane][16B] i8 splits (per-block-contiguous slice = 135,168 B)
#define WSLICE   135168u
#define OFF_W    0u
#define SZ_W     (128u*WSLICE)                      // 17,301,504
#define OFF_SC   SZ_W                               // inv_scale f32[2048]
#define OFF_SCF  (OFF_SC + 8192u)                   // scale     f32[2048]
#define OFF_ZB   (OFF_SCF + 8192u)                  // 2 x Z[16 b16][33 kk][64 lane][16] i8
#define ZBUF_B   (16u*KKT*1024u)                    // 540,672 B per buffer
#define OFF_XS   (OFF_ZB + 2u*ZBUF_B)               // [NT][NB][NI] i8 encoder spikes
#define SZ_XS    ((unsigned)NT*NB*NI)
#define OFF_PIO  (OFF_XS + SZ_XS)                   // 2 x [256 b][128 ht][4 o] f32
#define PIOHALF  (NB*128*NO)                        // floats per half
#define OFF_FLG  (OFF_PIO + 2u*PIOHALF*4u)          // arrive[256] u32

// per-row scales over [w_rec | w_in]: s = 30 - exp(rowmax) -> 4 signed bytes exact
__global__ __launch_bounds__(512) void k_scale(const float* __restrict__ w_rec,
                                               const float* __restrict__ w_in,
                                               char* __restrict__ wsb) {
    const int gt = blockIdx.x * 512 + threadIdx.x;   // 256 blocks -> 2048 waves
    const int h = gt >> 6, lane = gt & 63;
    float m = 0.0f;
    for (int k = lane; k < NH; k += 64) m = fmaxf(m, fabsf(w_rec[h * NH + k]));
    if (lane < 16) m = fmaxf(m, fabsf(w_in[h * NI + lane]));
    #pragma unroll
    for (int d = 1; d < 64; d <<= 1) m = fmaxf(m, __shfl_xor(m, d, 64));
    if (lane == 0) {
        int e;
        frexpf(m, &e);
        int s = 30 - e;
        ((float*)(wsb + OFF_SCF))[h] = ldexpf(1.0f, s);
        ((float*)(wsb + OFF_SC))[h]  = ldexpf(1.0f, -s);
    }
}

// quantize + split into 4 i8 planes, per-block-contiguous fragment layout
__global__ __launch_bounds__(192) void k_pack(const float* __restrict__ w_rec,
                                              const float* __restrict__ w_in,
                                              char* __restrict__ wsb) {
    const int h = blockIdx.x, c = threadIdx.x;       // 2048 blocks, 132 chunks of 16 k
    if (c >= 132) return;
    const float scale = ((const float*)(wsb + OFF_SCF))[h];
    const int k0 = c * 16;
    const int kk = k0 >> 6, q = (k0 >> 4) & 3;
    unsigned pk[4][4] = {{0u,0u,0u,0u},{0u,0u,0u,0u},{0u,0u,0u,0u},{0u,0u,0u,0u}};
    #pragma unroll
    for (int u = 0; u < 16; ++u) {
        int k = k0 + u;
        float wv = 0.0f;
        if (k < NH) wv = w_rec[h * NH + k];
        else if (k < NH + NI) wv = w_in[h * NI + (k - NH)];
        int wq = __float2int_rn(wv * scale);
        int b0_ = (wq << 24) >> 24;  int r = (wq - b0_) >> 8;
        int b1_ = (r << 24) >> 24;   r = (r - b1_) >> 8;
        int b2_ = (r << 24) >> 24;   int b3_ = (r - b2_) >> 8;
        int bs[4] = {b0_, b1_, b2_, b3_};
        #pragma unroll
        for (int sp = 0; sp < 4; ++sp)
            pk[sp][u >> 2] |= ((unsigned)(unsigned char)bs[sp]) << ((u & 3) * 8);
    }
    char* w4 = wsb + OFF_W;
    unsigned base = (((unsigned)(h >> 4)) * KKT + (unsigned)kk) * 4096u
                  + ((unsigned)q * 16u + (unsigned)(h & 15)) * 16u;
    #pragma unroll
    for (int sp = 0; sp < 4; ++sp)
        *(i32x4*)(w4 + base + (unsigned)sp * 1024u) = *(const i32x4*)pk[sp];
}

__global__ __launch_bounds__(256) void k_init(const float* __restrict__ x,
                                              char* __restrict__ wsb) {
    const int g = blockIdx.x * 256 + threadIdx.x;   // 65536 threads
    unsigned* zb32 = (unsigned*)(wsb + OFF_ZB);     // 270,336 uints (both buffers)
    char* xsp = (char*)(wsb + OFF_XS);

    #pragma unroll
    for (int r = 0; r < 5; ++r) {
        unsigned off = (unsigned)g + (unsigned)r * 65536u;
        if (off < (2u * ZBUF_B / 4u)) zb32[off] = 0u;
    }
    if (g < 256) ((unsigned*)(wsb + OFF_FLG))[g] = 0u;   // arrive flags

    if (g < NB * NI) {   // encoder cell (b, ci)
        const int b = g >> 4, ci = g & 15;
        float xv = x[b * ND + (ci & 7)];
        float c = (ci < 8) ? __fmul_rn(50.0f, xv) : __fmul_rn(-50.0f, xv);
        c = fmaxf(c, 0.0f);
        float ev = 0.0f;
        for (int t = 0; t < NT; ++t) {
            ev = __fadd_rn(ev, __fmul_rn(0.1f, __fsub_rn(c, ev)));
            float z = (__fsub_rn(ev, 1.0f) > 0.0f) ? 1.0f : 0.0f;
            xsp[t * (NB * NI) + g] = (z > 0.0f) ? (char)1 : (char)0;
            ev = (z > 0.0f) ? 0.0f : ev;
        }
    }
}

// xs[0] -> Z buffer 0 ext chunk (runs after k_init's zeroing)
__global__ __launch_bounds__(256) void k_init2(char* __restrict__ wsb) {
    const int b = threadIdx.x;                       // 256 threads
    char* zb0 = wsb + OFF_ZB;
    const char* xsp = wsb + OFF_XS;
    i32x4 xv = *(const i32x4*)(xsp + b * 16);
    *(i32x4*)(zb0 + (((unsigned)(b >> 4)) * KKT + 32u) * 1024u
                  + (unsigned)(b & 15) * 16u) = xv;
}

// persistent kernel: all 128 steps; weights in LDS; v/i in registers
__global__ __launch_bounds__(NTHR, 2) void k_persist(const float* __restrict__ w_out,
                                                     char* __restrict__ wsb,
                                                     float* __restrict__ out) {
    __shared__ char wlds[WSLICE];        // 135,168 B weight slice
    __shared__ float red[128 * 17];      // 8,704 B reduce / z staging / readout scratch
    __shared__ float woutlds[64];        // 4 o x 16 h

    const int tid = threadIdx.x;
    const int blk = blockIdx.x;
    const int bt = blk >> 7;             // 0..1  (128 b-rows each)
    const int ht = blk & 127;            // 0..127 (16 h each)
    const int h0 = ht * 16;

    char* zb = wsb + OFF_ZB;
    const char* xsp = wsb + OFF_XS;
    float* pio = (float*)(wsb + OFF_PIO);
    unsigned* arrive = (unsigned*)(wsb + OFF_FLG);
    const float* inv_scale = (const float*)(wsb + OFF_SC);

    // one-time: weight slice -> LDS (flat copy, identical layout)
    {
        const char* gW = wsb + OFF_W + (unsigned)ht * WSLICE;
        for (int i = tid; i < (int)(WSLICE / 16u); i += NTHR)
            *(i32x4*)(wlds + (unsigned)i * 16u) = *(const i32x4*)(gW + (unsigned)i * 16u);
    }
    if (tid < 64) woutlds[tid] = w_out[(tid >> 4) * NH + h0 + (tid & 15)];

    const int w = tid >> 6, lane = tid & 63;
    const int kw = w & 1, bw = w >> 1;   // 2 K-halves x 4 b-groups
    const int lk = lane >> 4, lh = lane & 15;
    const unsigned lane16 = (unsigned)lane * 16u;
    const float inv = inv_scale[h0 + lh];

    // per-thread LIF state: b_local = tid>>2, h = h0 + (tid&3)*4 + j
    float vmem[4] = {0.f, 0.f, 0.f, 0.f}, icur[4] = {0.f, 0.f, 0.f, 0.f};
    // readout owner state (ht<8, tid<64): b = bt*128 + ht + (tid>>2)*8, o = tid&3
    float vo = 0.0f, io = 0.0f, mxv = -3.0e38f;

    __syncthreads();

    for (int t = 0; t < NT; ++t) {
        const char* zr = zb + (t & 1) * ZBUF_B;
        char* zw = zb + ((t + 1) & 1) * ZBUF_B;
        float* pw = pio + (t & 1) * PIOHALF;

        // (1a) LI readout helpers: 8 partial sums per (b,o) cell -> red[c*8+h]
        if (t > 0 && ht < 8) {
            const int hh = tid >> 6;         // 0..7
            const int c = tid & 63;          // cell
            const int bg = bt * 128 + ht + (c >> 2) * 8;
            const int o = c & 3;
            const float* pr = pio + ((t - 1) & 1) * PIOHALF + (unsigned)bg * 512u + o;
            float s = 0.0f;
            #pragma unroll
            for (int j = 0; j < 16; ++j) s += pr[(hh * 16 + j) * 4];
            red[c * 8 + hh] = s;
        }
        __syncthreads();
        // (1b) owners: combine partials, LI update
        if (t > 0 && ht < 8 && tid < 64) {
            float s = 0.0f;
            #pragma unroll
            for (int hh = 0; hh < 8; ++hh) s += red[tid * 8 + hh];
            float von = __fadd_rn(vo, __fmul_rn(0.1f, __fsub_rn(io, vo)));  // old io
            io = __fadd_rn(__fmul_rn(io, 0.8f), s);
            vo = von;
            mxv = fmaxf(mxv, von);
        }
        __syncthreads();   // red free for GEMM reduce

        // (2) xs[t+1] -> next z-buffer ext chunk (one block per bt group)
        if (ht == 8 && t + 1 < NT && tid < 128) {
            const int bg = bt * 128 + tid;
            i32x4 xv = *(const i32x4*)(xsp + ((t + 1) * NB + bg) * 16);
            *(i32x4*)(zw + (((unsigned)(bg >> 4)) * KKT + 32u) * 1024u
                         + (unsigned)(bg & 15) * 16u) = xv;
        }

        // (3) i8 MFMA GEMM: wave (kw,bw) = K-half x 2 b16; depth-6 rolling A prefetch
        i32x4 acc[2][4];
        #pragma unroll
        for (int rb = 0; rb < 2; ++rb)
            #pragma unroll
            for (int sp = 0; sp < 4; ++sp) acc[rb][sp] = (i32x4){0, 0, 0, 0};

        const char* zA = zr + ((unsigned)(bt * 8 + bw * 2) * KKT) * 1024u + lane16;
        const int kkbeg = kw * 17;
        const int trips = 17 - kw;       // kw0: kk 0..16, kw1: kk 17..32

        i64x2 abuf[DPF][2];
        #pragma unroll
        for (int p = 0; p < DPF; ++p) {
            if (p < trips) {
                const unsigned o = (unsigned)(kkbeg + p) * 1024u;
                abuf[p][0] = *(const i64x2*)(zA + o);
                abuf[p][1] = *(const i64x2*)(zA + (unsigned)KKT * 1024u + o);
            }
        }
        #pragma unroll
        for (int kx = 0; kx < 17; ++kx) {
            if (kx < trips) {
                const int slot = kx % DPF;
                i64x2 a0 = abuf[slot][0];
                i64x2 a1 = abuf[slot][1];
                if (kx + DPF < trips) {
                    const unsigned on = (unsigned)(kkbeg + kx + DPF) * 1024u;
                    abuf[slot][0] = *(const i64x2*)(zA + on);
                    abuf[slot][1] = *(const i64x2*)(zA + (unsigned)KKT * 1024u + on);
                }
                const unsigned o = (unsigned)(kkbeg + kx) * 1024u;
                #pragma unroll
                for (int sp = 0; sp < 4; ++sp) {
                    i64x2 bf = *(const i64x2*)(wlds + o * 4u + ((unsigned)sp << 10) + lane16);
                    acc[0][sp] = __builtin_amdgcn_mfma_i32_16x16x32_i8(
                        a0[0], bf[0], acc[0][sp], 0, 0, 0);
                    acc[0][sp] = __builtin_amdgcn_mfma_i32_16x16x32_i8(
                        a0[1], bf[1], acc[0][sp], 0, 0, 0);
                    acc[1][sp] = __builtin_amdgcn_mfma_i32_16x16x32_i8(
                        a1[0], bf[0], acc[1][sp], 0, 0, 0);
                    acc[1][sp] = __builtin_amdgcn_mfma_i32_16x16x32_i8(
                        a1[1], bf[1], acc[1][sp], 0, 0, 0);
                }
            }
        }

        // combine splits -> f32, two-phase cross-kw reduce in LDS
        float fc[2][4];
        #pragma unroll
        for (int rb = 0; rb < 2; ++rb)
            #pragma unroll
            for (int r = 0; r < 4; ++r) {
                float f = fmaf((float)acc[rb][3][r], 16777216.0f,
                          fmaf((float)acc[rb][2][r], 65536.0f,
                          fmaf((float)acc[rb][1][r], 256.0f,
                               (float)acc[rb][0][r])));
                fc[rb][r] = f * inv;
            }
        if (kw == 1) {
            #pragma unroll
            for (int rb = 0; rb < 2; ++rb)
                #pragma unroll
                for (int r = 0; r < 4; ++r)
                    red[((bw * 2 + rb) * 16 + lk * 4 + r) * 17 + lh] = fc[rb][r];
        }
        __syncthreads();
        if (kw == 0) {
            #pragma unroll
            for (int rb = 0; rb < 2; ++rb)
                #pragma unroll
                for (int r = 0; r < 4; ++r) {
                    int ro = ((bw * 2 + rb) * 16 + lk * 4 + r) * 17 + lh;
                    red[ro] = fc[rb][r] + red[ro];
                }
        }
        __syncthreads();

        // (4) LIF update (v,i in registers); z bits back into red
        const int bb = tid >> 2, hb4 = (tid & 3) * 4;
        float zn4[4];
        #pragma unroll
        for (int j = 0; j < 4; ++j) {
            float accv = red[bb * 17 + hb4 + j];
            float vd = __fadd_rn(vmem[j], __fmul_rn(0.1f, __fsub_rn(icur[j], vmem[j])));
            float zn = (__fsub_rn(vd, 1.0f) > 0.0f) ? 1.0f : 0.0f;
            vmem[j] = (zn > 0.0f) ? 0.0f : vd;
            icur[j] = __fadd_rn(__fmul_rn(icur[j], 0.8f), accv);   // c folded in GEMM
            zn4[j] = zn;
        }
        #pragma unroll
        for (int j = 0; j < 4; ++j) red[bb * 17 + hb4 + j] = zn4[j];
        __syncthreads();

        // (5) readout partial + z-fragment write
        {
            const int o = tid & 3;
            float s = 0.0f;
            #pragma unroll
            for (int h = 0; h < 16; ++h)
                s = fmaf(red[bb * 17 + h], woutlds[o * 16 + h], s);
            pw[(((unsigned)(bt * 128 + bb)) * 128u + (unsigned)ht) * 4u + (unsigned)o] = s;
        }
        if (tid < 128) {
            const int bg = bt * 128 + tid;
            unsigned uw[4] = {0u, 0u, 0u, 0u};
            #pragma unroll
            for (int h = 0; h < 16; ++h)
                uw[h >> 2] |= (red[tid * 17 + h] > 0.5f ? 1u : 0u) << ((h & 3) * 8);
            i32x4 zv = {(int)uw[0], (int)uw[1], (int)uw[2], (int)uw[3]};
            *(i32x4*)(zw + (((unsigned)(bg >> 4)) * KKT + (unsigned)(ht >> 2)) * 1024u
                         + ((unsigned)(ht & 3) * 16u + (unsigned)(bg & 15)) * 16u) = zv;
        }

        // (6) per-bt single-hop barrier; one wbl2/invl2 per block per step
        __syncthreads();   // all stores issued (compiler drains vmcnt before barrier)
        if (tid == 0) {
            __builtin_amdgcn_fence(__ATOMIC_RELEASE, "agent");   // buffer_wbl2
            __hip_atomic_store(&arrive[blk], (unsigned)(t + 1),
                               __ATOMIC_RELAXED, __HIP_MEMORY_SCOPE_AGENT);
        }
        if (tid < 128) {
            const unsigned tgt = (unsigned)(t + 1);
            while (__hip_atomic_load(&arrive[bt * 128 + tid], __ATOMIC_RELAXED,
                                     __HIP_MEMORY_SCOPE_AGENT) < tgt)
                __builtin_amdgcn_s_sleep(1);
        }
        __syncthreads();
        if (tid == 0)
            __builtin_amdgcn_fence(__ATOMIC_ACQUIRE, "agent");   // buffer_inv
        __syncthreads();
    }

    // final voltage[127] + softmax (owners)
    if (ht < 8 && tid < 64) {
        float von = __fadd_rn(vo, __fmul_rn(0.1f, __fsub_rn(io, vo)));
        float mx = fmaxf(mxv, von);
        float mm = fmaxf(mx, __shfl_xor(mx, 1, 64));
        mm = fmaxf(mm, __shfl_xor(mm, 2, 64));
        float e = expf(__fsub_rn(mx, mm));
        float es = e;
        es += __shfl_xor(es, 1, 64);
        es += __shfl_xor(es, 2, 64);
        const int bg = bt * 128 + ht + (tid >> 2) * 8;
        out[bg * 4 + (tid & 3)] = e / es;
    }
}

extern "C" void kernel_launch(void* const* d_in, const int* in_sizes, int n_in,
                              void* d_out, int out_size, void* d_ws, size_t ws_size,
                              hipStream_t stream) {
    const float* x     = (const float*)d_in[0];
    const float* w_in  = (const float*)d_in[1];
    const float* w_rec = (const float*)d_in[2];
    const float* w_out = (const float*)d_in[3];
    float* out = (float*)d_out;
    char* wsb  = (char*)d_ws;

    k_scale<<<256, 512, 0, stream>>>(w_rec, w_in, wsb);
    k_pack<<<NH, 192, 0, stream>>>(w_rec, w_in, wsb);
    k_init<<<256, 256, 0, stream>>>(x, wsb);
    k_init2<<<1, 256, 0, stream>>>(wsb);
    k_persist<<<NBLK, NTHR, 0, stream>>>(w_out, wsb, out);
}

// Round 14
// 1618.112 us; speedup vs baseline: 1.6257x; 1.6257x over previous
//
#include <hip/hip_runtime.h>
#include <math.h>

#define NB 256
#define NH 2048
#define ND 8
#define NI 16
#define NT 128
#define NO 4
#define KKT 33           // K chunks of 64: 32 rec + 1 ext (w_in + zero pad) -> K = 2112
#define NTHR 512
#define NBLK 512

typedef __attribute__((ext_vector_type(4))) int i32x4;
typedef __attribute__((ext_vector_type(2))) long i64x2;

// ---- ws byte offsets ----
// W4: 4 i8 splits x [128 h16][33 kk][64 lane][16] (fragment-linear)
#define SSTR     (128u*KKT*1024u)                   // one split = 4,325,376 B
#define OFF_W4   0u
#define SZ_W4    (4u*SSTR)                          // 17,301,504
#define OFF_SC   (OFF_W4 + SZ_W4)                   // inv_scale f32[2048]
#define OFF_SCF  (OFF_SC + 8192u)                   // scale     f32[2048]
#define ZBUF_B   (16u*KKT*1024u)                    // 540,672 B per z buffer
#define OFF_ZB   (OFF_SCF + 8192u)                  // 2 x Z[16 b16][33 kk][64 lane][16] i8
#define SZ_ZB    (2u*ZBUF_B)
#define OFF_XS   (OFF_ZB + SZ_ZB)                   // [NT][NB][NI] i8 encoder spikes
#define SZ_XS    ((unsigned)NT*NB*NI)
#define OFF_V    (OFF_XS + SZ_XS)                   // [NB][NH] f32
#define SZ_V     ((unsigned)NB*NH*4u)
#define OFF_I    (OFF_V + SZ_V)
#define OFF_PIO  (OFF_I + SZ_V)                     // 2 x [256 b][64 ht][4 o] f32
#define PIOHALF  (NB*64*NO)                         // floats per half
#define OFF_VIO  (OFF_PIO + 2u*PIOHALF*4u)          // vo[1024], io[1024], mx[1024]

// per-row scales over [w_rec | w_in]: s = 30 - exp(rowmax) -> 4 signed bytes exact
__global__ __launch_bounds__(512) void k_scale(const float* __restrict__ w_rec,
                                               const float* __restrict__ w_in,
                                               char* __restrict__ wsb) {
    const int gt = blockIdx.x * 512 + threadIdx.x;   // 256 blocks -> 2048 waves
    const int h = gt >> 6, lane = gt & 63;
    float m = 0.0f;
    for (int k = lane; k < NH; k += 64) m = fmaxf(m, fabsf(w_rec[h * NH + k]));
    if (lane < 16) m = fmaxf(m, fabsf(w_in[h * NI + lane]));
    #pragma unroll
    for (int d = 1; d < 64; d <<= 1) m = fmaxf(m, __shfl_xor(m, d, 64));
    if (lane == 0) {
        int e;
        frexpf(m, &e);           // m = f*2^e, f in [0.5,1)
        int s = 30 - e;
        ((float*)(wsb + OFF_SCF))[h] = ldexpf(1.0f, s);
        ((float*)(wsb + OFF_SC))[h]  = ldexpf(1.0f, -s);
    }
}

// quantize + split into 4 i8 planes, fragment-linear
__global__ __launch_bounds__(192) void k_pack(const float* __restrict__ w_rec,
                                              const float* __restrict__ w_in,
                                              char* __restrict__ wsb) {
    const int h = blockIdx.x, c = threadIdx.x;       // 2048 blocks, 132 chunks of 16 k
    if (c >= 132) return;
    const float scale = ((const float*)(wsb + OFF_SCF))[h];
    const int k0 = c * 16;
    const int kk = k0 >> 6, q = (k0 >> 4) & 3;
    unsigned pk[4][4] = {{0u,0u,0u,0u},{0u,0u,0u,0u},{0u,0u,0u,0u},{0u,0u,0u,0u}};
    #pragma unroll
    for (int u = 0; u < 16; ++u) {
        int k = k0 + u;
        float wv = 0.0f;
        if (k < NH) wv = w_rec[h * NH + k];
        else if (k < NH + NI) wv = w_in[h * NI + (k - NH)];
        int wq = __float2int_rn(wv * scale);
        int b0_ = (wq << 24) >> 24;  int r = (wq - b0_) >> 8;
        int b1_ = (r << 24) >> 24;   r = (r - b1_) >> 8;
        int b2_ = (r << 24) >> 24;   int b3_ = (r - b2_) >> 8;
        int bs[4] = {b0_, b1_, b2_, b3_};
        #pragma unroll
        for (int sp = 0; sp < 4; ++sp)
            pk[sp][u >> 2] |= ((unsigned)(unsigned char)bs[sp]) << ((u & 3) * 8);
    }
    char* w4 = wsb + OFF_W4;
    unsigned base = (((unsigned)(h >> 4)) * KKT + (unsigned)kk) * 1024u
                  + ((unsigned)q * 16u + (unsigned)(h & 15)) * 16u;
    #pragma unroll
    for (int sp = 0; sp < 4; ++sp)
        *(i32x4*)(w4 + (unsigned)sp * SSTR + base) = *(const i32x4*)pk[sp];
}

__global__ __launch_bounds__(256) void k_init(const float* __restrict__ x,
                                              char* __restrict__ wsb) {
    const int g = blockIdx.x * 256 + threadIdx.x;   // 65536 threads
    unsigned* zb32 = (unsigned*)(wsb + OFF_ZB);     // 270,336 uints
    float* vst = (float*)(wsb + OFF_V);
    float* ist = (float*)(wsb + OFF_I);
    float* vio = (float*)(wsb + OFF_VIO);
    char* xsp = (char*)(wsb + OFF_XS);

    #pragma unroll
    for (int r = 0; r < 5; ++r) {
        unsigned off = (unsigned)g + (unsigned)r * 65536u;
        if (off < (SZ_ZB / 4u)) zb32[off] = 0u;
    }
    #pragma unroll
    for (int r = 0; r < 8; ++r) vst[g + r * 65536] = 0.0f;
    #pragma unroll
    for (int r = 0; r < 8; ++r) ist[g + r * 65536] = 0.0f;
    if (g < 3072) vio[g] = (g < 2048) ? 0.0f : -3.0e38f;

    if (g < NB * NI) {   // encoder cell (b, ci)
        const int b = g >> 4, ci = g & 15;
        float xv = x[b * ND + (ci & 7)];
        float c = (ci < 8) ? __fmul_rn(50.0f, xv) : __fmul_rn(-50.0f, xv);
        c = fmaxf(c, 0.0f);
        float ev = 0.0f;
        for (int t = 0; t < NT; ++t) {
            ev = __fadd_rn(ev, __fmul_rn(0.1f, __fsub_rn(c, ev)));
            float z = (__fsub_rn(ev, 1.0f) > 0.0f) ? 1.0f : 0.0f;
            xsp[t * (NB * NI) + g] = (z > 0.0f) ? (char)1 : (char)0;
            ev = (z > 0.0f) ? 0.0f : ev;
        }
    }
}

// xs[0] -> Z buffer 0 ext chunk (kk=32, q=0)
__global__ __launch_bounds__(256) void k_init2(char* __restrict__ wsb) {
    const int b = threadIdx.x;                       // 256 threads
    char* zb0 = wsb + OFF_ZB;
    const char* xsp = wsb + OFF_XS;
    i32x4 xv = *(const i32x4*)(xsp + b * 16);
    *(i32x4*)(zb0 + (((unsigned)(b >> 4)) * KKT + 32u) * 1024u
                  + (unsigned)(b & 15) * 16u) = xv;
}

// 512 blocks x 512 thr (2 blocks/CU, 16 waves/CU): tile 32b x 32h, waves stride K by 8
__global__ __launch_bounds__(NTHR, 4) void k_step(const float* __restrict__ w_out,
                                                  char* __restrict__ wsb, int t) {
    __shared__ float red[4][32 * 33];    // 4 k-partial buffers (two-phase reduce)
    __shared__ float z_s[32 * 33];
    __shared__ float w_out_lds[128];     // LDS total = 21,632 B

    const int tid = threadIdx.x;
    const int blk = blockIdx.x;
    const int xcd = blk & 7, j = blk >> 3;
    const int ht = xcd * 8 + (j & 7);    // 0..63 (h-tile, XCD-local weights)
    const int bt = j >> 3;               // 0..7
    const int b0 = bt * 32, h0 = ht * 32;

    const char* w4 = wsb + OFF_W4;
    const float* inv_scale = (const float*)(wsb + OFF_SC);
    char* zb = wsb + OFF_ZB;
    const char* xsp = wsb + OFF_XS;
    float* vst = (float*)(wsb + OFF_V);
    float* ist = (float*)(wsb + OFF_I);
    float* pio = (float*)(wsb + OFF_PIO);
    float* vio = (float*)(wsb + OFF_VIO);

    const char* zr = zb + (t & 1) * ZBUF_B;
    char* zw = zb + ((t + 1) & 1) * ZBUF_B;

    // LI readout update for step t-1 (blocks 0-1 cover all 1024 (b,o) cells)
    const int g = blk * NTHR + tid;
    if (t > 0 && g < NB * NO) {
        const float* pr = pio + ((t - 1) & 1) * PIOHALF;
        const int b = g >> 2, o = g & 3;
        float s = 0.0f;
        #pragma unroll
        for (int jj = 0; jj < 64; ++jj) s += pr[b * 256 + jj * 4 + o];
        float vo = vio[g], io = vio[1024 + g], mx = vio[2048 + g];
        float von = __fadd_rn(vo, __fmul_rn(0.1f, __fsub_rn(io, vo)));  // old io
        io = __fadd_rn(__fmul_rn(io, 0.8f), s);
        vio[g] = von; vio[1024 + g] = io; vio[2048 + g] = fmaxf(mx, von);
    }

    // xs[t+1] -> next Z ext chunk (ht==8 blocks: 8 x 32 rows = all 256)
    if (ht == 8 && t + 1 < NT && tid < 32) {
        const int bg = b0 + tid;
        i32x4 xv = *(const i32x4*)(xsp + ((t + 1) * NB + bg) * 16);
        *(i32x4*)(zw + (((unsigned)(bg >> 4)) * KKT + 32u) * 1024u
                     + (unsigned)(bg & 15) * 16u) = xv;
    }
    if (tid < 128) w_out_lds[tid] = w_out[(tid >> 5) * NH + h0 + (tid & 31)];

    // ---- i8 MFMA GEMM: 8 waves stride K chunks by 8; 4 splits; 32b x 32h tile
    const int w = tid >> 6, lane = tid & 63;
    const unsigned lane16 = (unsigned)lane * 16u;

    i32x4 acc[2][2][4];   // [rb][hb][split]
    #pragma unroll
    for (int rb = 0; rb < 2; ++rb)
        #pragma unroll
        for (int hb = 0; hb < 2; ++hb)
            #pragma unroll
            for (int sp = 0; sp < 4; ++sp) acc[rb][hb][sp] = (i32x4){0, 0, 0, 0};

    const char* zA = zr + ((unsigned)(bt * 2) * KKT) * 1024u + lane16;   // rb stride KKT KB
    const char* wB = w4 + ((unsigned)(ht * 2) * KKT) * 1024u + lane16;   // hb stride KKT KB
    const unsigned rstr = (unsigned)KKT * 1024u;

    for (int kk = w; kk < KKT; kk += 8) {
        const unsigned o = (unsigned)kk * 1024u;
        i64x2 a0 = *(const i64x2*)(zA + o);
        i64x2 a1 = *(const i64x2*)(zA + rstr + o);
        #pragma unroll
        for (int sp = 0; sp < 4; ++sp) {
            #pragma unroll
            for (int hb = 0; hb < 2; ++hb) {
                i64x2 bf = *(const i64x2*)(wB + (unsigned)sp * SSTR
                                              + (unsigned)hb * rstr + o);
                acc[0][hb][sp] = __builtin_amdgcn_mfma_i32_16x16x32_i8(
                    a0[0], bf[0], acc[0][hb][sp], 0, 0, 0);
                acc[0][hb][sp] = __builtin_amdgcn_mfma_i32_16x16x32_i8(
                    a0[1], bf[1], acc[0][hb][sp], 0, 0, 0);
                acc[1][hb][sp] = __builtin_amdgcn_mfma_i32_16x16x32_i8(
                    a1[0], bf[0], acc[1][hb][sp], 0, 0, 0);
                acc[1][hb][sp] = __builtin_amdgcn_mfma_i32_16x16x32_i8(
                    a1[1], bf[1], acc[1][hb][sp], 0, 0, 0);
            }
        }
    }

    // combine splits -> f32, two-phase cross-wave reduce
    const int lk = lane >> 4, lh = lane & 15;
    const float inv0 = inv_scale[h0 + lh], inv1 = inv_scale[h0 + 16 + lh];
    float fc[2][2][4];
    #pragma unroll
    for (int rb = 0; rb < 2; ++rb)
        #pragma unroll
        for (int hb = 0; hb < 2; ++hb) {
            float invs = hb ? inv1 : inv0;
            #pragma unroll
            for (int r = 0; r < 4; ++r) {
                float f = fmaf((float)acc[rb][hb][3][r], 16777216.0f,
                          fmaf((float)acc[rb][hb][2][r], 65536.0f,
                          fmaf((float)acc[rb][hb][1][r], 256.0f,
                               (float)acc[rb][hb][0][r])));
                fc[rb][hb][r] = f * invs;
            }
        }
    if (w >= 4) {
        #pragma unroll
        for (int rb = 0; rb < 2; ++rb)
            #pragma unroll
            for (int hb = 0; hb < 2; ++hb)
                #pragma unroll
                for (int r = 0; r < 4; ++r)
                    red[w - 4][(rb * 16 + lk * 4 + r) * 33 + hb * 16 + lh]
                        = fc[rb][hb][r];
    }
    __syncthreads();
    if (w < 4) {
        #pragma unroll
        for (int rb = 0; rb < 2; ++rb)
            #pragma unroll
            for (int hb = 0; hb < 2; ++hb)
                #pragma unroll
                for (int r = 0; r < 4; ++r) {
                    int ro = (rb * 16 + lk * 4 + r) * 33 + hb * 16 + lh;
                    red[w][ro] = fc[rb][hb][r] + red[w][ro];
                }
    }
    __syncthreads();

    // reduce 4 buffers + LIF update (2 elems/thread: 1024 = 32b x 32h)
    #pragma unroll
    for (int e = 0; e < 2; ++e) {
        int idx = e * NTHR + tid;
        int bl = idx >> 5, hl = idx & 31;
        int ro = bl * 33 + hl;
        float accv = ((red[0][ro] + red[1][ro]) + red[2][ro]) + red[3][ro];
        int gidx = (b0 + bl) * NH + h0 + hl;
        float vv = vst[gidx], ii = ist[gidx];
        float vd = __fadd_rn(vv, __fmul_rn(0.1f, __fsub_rn(ii, vv)));
        float zn = (__fsub_rn(vd, 1.0f) > 0.0f) ? 1.0f : 0.0f;
        vst[gidx] = (zn > 0.0f) ? 0.0f : vd;
        ist[gidx] = __fadd_rn(__fmul_rn(ii, 0.8f), accv);   // input current in GEMM ext
        z_s[ro] = zn;
    }
    __syncthreads();

    // spikes -> Z (this block owns chunk kk=ht>>1, q-pair ht&1) + readout partials
    if (tid < 256) {
        const int b = tid >> 3, seg = tid & 7;    // h = seg*4 .. +3
        const int bg = b0 + b;
        unsigned uw = 0;
        #pragma unroll
        for (int jj = 0; jj < 4; ++jj)
            uw |= (z_s[b * 33 + seg * 4 + jj] > 0.5f ? 1u : 0u) << (jj * 8);
        const unsigned q = (unsigned)((ht & 1) * 2 + (seg >> 2));
        *(unsigned*)(zw + (((unsigned)(bg >> 4)) * KKT + (unsigned)(ht >> 1)) * 1024u
                        + (q * 16u + (unsigned)(bg & 15)) * 16u + (unsigned)((seg & 3) * 4))
            = uw;
    }
    if (tid < 128) {
        const int b = tid >> 2, o = tid & 3;
        float s = 0.0f;
        #pragma unroll
        for (int h = 0; h < 32; ++h)
            s = fmaf(z_s[b * 33 + h], w_out_lds[o * 32 + h], s);
        float* pw = pio + (t & 1) * PIOHALF;
        pw[(b0 + b) * 256 + ht * 4 + o] = s;
    }
}

__global__ __launch_bounds__(256) void k_final(char* __restrict__ wsb,
                                               float* __restrict__ out) {
    const int g = blockIdx.x * 256 + threadIdx.x;   // 1024 threads (4 blocks!)
    if (g >= NB * NO) return;
    float* vio = (float*)(wsb + OFF_VIO);
    float vo = vio[g], io = vio[1024 + g], mx = vio[2048 + g];
    float von = __fadd_rn(vo, __fmul_rn(0.1f, __fsub_rn(io, vo)));
    mx = fmaxf(mx, von);

    float mm = fmaxf(mx, __shfl_xor(mx, 1, 64));
    mm = fmaxf(mm, __shfl_xor(mm, 2, 64));
    float e = expf(__fsub_rn(mx, mm));
    float es = e;
    es += __shfl_xor(es, 1, 64);
    es += __shfl_xor(es, 2, 64);
    out[g] = e / es;
}

extern "C" void kernel_launch(void* const* d_in, const int* in_sizes, int n_in,
                              void* d_out, int out_size, void* d_ws, size_t ws_size,
                              hipStream_t stream) {
    const float* x     = (const float*)d_in[0];
    const float* w_in  = (const float*)d_in[1];
    const float* w_rec = (const float*)d_in[2];
    const float* w_out = (const float*)d_in[3];
    float* out = (float*)d_out;
    char* wsb  = (char*)d_ws;

    k_scale<<<256, 512, 0, stream>>>(w_rec, w_in, wsb);
    k_pack<<<NH, 192, 0, stream>>>(w_rec, w_in, wsb);
    k_init<<<256, 256, 0, stream>>>(x, wsb);
    k_init2<<<1, 256, 0, stream>>>(wsb);
    for (int t = 0; t < NT; ++t)
        k_step<<<NBLK, NTHR, 0, stream>>>(w_out, wsb, t);
    k_final<<<4, 256, 0, stream>>>(wsb, out);
}

// Round 15
// 1463.989 us; speedup vs baseline: 1.7968x; 1.1053x over previous
//
#include <hip/hip_runtime.h>
#include <math.h>

#define NB 256
#define NH 2048
#define ND 8
#define NI 16
#define NT 128
#define NO 4
#define KKT 33           // K chunks of 64: 32 rec + 1 ext (w_in + zero pad) -> K = 2112
#define NTHR 512
#define NBLK 512

typedef __attribute__((ext_vector_type(4))) int i32x4;
typedef __attribute__((ext_vector_type(2))) long i64x2;

// ---- ws byte offsets ----
// W3: 3 i8 splits x [128 h16][33 kk][64 lane][16] (fragment-linear)
#define SSTR     (128u*KKT*1024u)                   // one split = 4,325,376 B
#define OFF_W3   0u
#define SZ_W3    (3u*SSTR)                          // 12,976,128
#define OFF_SC   (OFF_W3 + SZ_W3)                   // inv_scale f32[2048]
#define OFF_SCF  (OFF_SC + 8192u)                   // scale     f32[2048]
#define ZBUF_B   (16u*KKT*1024u)                    // 540,672 B per z buffer
#define OFF_ZB   (OFF_SCF + 8192u)                  // 2 x Z[16 b16][33 kk][64 lane][16] i8
#define SZ_ZB    (2u*ZBUF_B)
#define OFF_XS   (OFF_ZB + SZ_ZB)                   // [NT][NB][NI] i8 encoder spikes
#define SZ_XS    ((unsigned)NT*NB*NI)
#define OFF_V    (OFF_XS + SZ_XS)                   // [NB][NH] f32
#define SZ_V     ((unsigned)NB*NH*4u)
#define OFF_I    (OFF_V + SZ_V)
#define OFF_PIO  (OFF_I + SZ_V)                     // 2 x [256 b][64 ht][4 o] f32
#define PIOHALF  (NB*64*NO)                         // floats per half
#define OFF_VIO  (OFF_PIO + 2u*PIOHALF*4u)          // vo[1024], io[1024], mx[1024]

// per-row scales over [w_rec | w_in]: s = 22 - exp(rowmax) -> |w*2^s| < 2^23, 3 bytes
__global__ __launch_bounds__(512) void k_scale(const float* __restrict__ w_rec,
                                               const float* __restrict__ w_in,
                                               char* __restrict__ wsb) {
    const int gt = blockIdx.x * 512 + threadIdx.x;   // 256 blocks -> 2048 waves
    const int h = gt >> 6, lane = gt & 63;
    float m = 0.0f;
    for (int k = lane; k < NH; k += 64) m = fmaxf(m, fabsf(w_rec[h * NH + k]));
    if (lane < 16) m = fmaxf(m, fabsf(w_in[h * NI + lane]));
    #pragma unroll
    for (int d = 1; d < 64; d <<= 1) m = fmaxf(m, __shfl_xor(m, d, 64));
    if (lane == 0) {
        int e;
        frexpf(m, &e);           // m = f*2^e, f in [0.5,1)
        int s = 22 - e;
        ((float*)(wsb + OFF_SCF))[h] = ldexpf(1.0f, s);
        ((float*)(wsb + OFF_SC))[h]  = ldexpf(1.0f, -s);
    }
}

// quantize + split into 3 i8 planes, fragment-linear
__global__ __launch_bounds__(192) void k_pack(const float* __restrict__ w_rec,
                                              const float* __restrict__ w_in,
                                              char* __restrict__ wsb) {
    const int h = blockIdx.x, c = threadIdx.x;       // 2048 blocks, 132 chunks of 16 k
    if (c >= 132) return;
    const float scale = ((const float*)(wsb + OFF_SCF))[h];
    const int k0 = c * 16;
    const int kk = k0 >> 6, q = (k0 >> 4) & 3;
    unsigned pk[3][4] = {{0u,0u,0u,0u},{0u,0u,0u,0u},{0u,0u,0u,0u}};
    #pragma unroll
    for (int u = 0; u < 16; ++u) {
        int k = k0 + u;
        float wv = 0.0f;
        if (k < NH) wv = w_rec[h * NH + k];
        else if (k < NH + NI) wv = w_in[h * NI + (k - NH)];
        int wq = __float2int_rn(wv * scale);
        int b0_ = (wq << 24) >> 24;  int r = (wq - b0_) >> 8;
        int b1_ = (r << 24) >> 24;   int b2_ = (r - b1_) >> 8;
        int bs[3] = {b0_, b1_, b2_};
        #pragma unroll
        for (int sp = 0; sp < 3; ++sp)
            pk[sp][u >> 2] |= ((unsigned)(unsigned char)bs[sp]) << ((u & 3) * 8);
    }
    char* w3 = wsb + OFF_W3;
    unsigned base = (((unsigned)(h >> 4)) * KKT + (unsigned)kk) * 1024u
                  + ((unsigned)q * 16u + (unsigned)(h & 15)) * 16u;
    #pragma unroll
    for (int sp = 0; sp < 3; ++sp)
        *(i32x4*)(w3 + (unsigned)sp * SSTR + base) = *(const i32x4*)pk[sp];
}

__global__ __launch_bounds__(256) void k_init(const float* __restrict__ x,
                                              char* __restrict__ wsb) {
    const int g = blockIdx.x * 256 + threadIdx.x;   // 65536 threads
    unsigned* zb32 = (unsigned*)(wsb + OFF_ZB);     // 270,336 uints
    float* vst = (float*)(wsb + OFF_V);
    float* ist = (float*)(wsb + OFF_I);
    float* vio = (float*)(wsb + OFF_VIO);
    char* xsp = (char*)(wsb + OFF_XS);

    #pragma unroll
    for (int r = 0; r < 5; ++r) {
        unsigned off = (unsigned)g + (unsigned)r * 65536u;
        if (off < (SZ_ZB / 4u)) zb32[off] = 0u;
    }
    #pragma unroll
    for (int r = 0; r < 8; ++r) vst[g + r * 65536] = 0.0f;
    #pragma unroll
    for (int r = 0; r < 8; ++r) ist[g + r * 65536] = 0.0f;
    if (g < 3072) vio[g] = (g < 2048) ? 0.0f : -3.0e38f;

    if (g < NB * NI) {   // encoder cell (b, ci)
        const int b = g >> 4, ci = g & 15;
        float xv = x[b * ND + (ci & 7)];
        float c = (ci < 8) ? __fmul_rn(50.0f, xv) : __fmul_rn(-50.0f, xv);
        c = fmaxf(c, 0.0f);
        float ev = 0.0f;
        for (int t = 0; t < NT; ++t) {
            ev = __fadd_rn(ev, __fmul_rn(0.1f, __fsub_rn(c, ev)));
            float z = (__fsub_rn(ev, 1.0f) > 0.0f) ? 1.0f : 0.0f;
            xsp[t * (NB * NI) + g] = (z > 0.0f) ? (char)1 : (char)0;
            ev = (z > 0.0f) ? 0.0f : ev;
        }
    }
}

// xs[0] -> Z buffer 0 ext chunk (kk=32, q=0)
__global__ __launch_bounds__(256) void k_init2(char* __restrict__ wsb) {
    const int b = threadIdx.x;                       // 256 threads
    char* zb0 = wsb + OFF_ZB;
    const char* xsp = wsb + OFF_XS;
    i32x4 xv = *(const i32x4*)(xsp + b * 16);
    *(i32x4*)(zb0 + (((unsigned)(b >> 4)) * KKT + 32u) * 1024u
                  + (unsigned)(b & 15) * 16u) = xv;
}

// 512 blocks x 512 thr (2 blocks/CU, 16 waves/CU): tile 32b x 32h, waves stride K by 8
__global__ __launch_bounds__(NTHR, 4) void k_step(const float* __restrict__ w_out,
                                                  char* __restrict__ wsb, int t) {
    __shared__ float red[4][32 * 33];    // 4 k-partial buffers (two-phase reduce)
    __shared__ float z_s[32 * 33];
    __shared__ float w_out_lds[128];     // LDS total = 21,632 B

    const int tid = threadIdx.x;
    const int blk = blockIdx.x;
    const int xcd = blk & 7, j = blk >> 3;
    const int ht = xcd * 8 + (j & 7);    // 0..63 (h-tile, XCD-local weights)
    const int bt = j >> 3;               // 0..7
    const int b0 = bt * 32, h0 = ht * 32;

    const char* w3 = wsb + OFF_W3;
    const float* inv_scale = (const float*)(wsb + OFF_SC);
    char* zb = wsb + OFF_ZB;
    const char* xsp = wsb + OFF_XS;
    float* vst = (float*)(wsb + OFF_V);
    float* ist = (float*)(wsb + OFF_I);
    float* pio = (float*)(wsb + OFF_PIO);
    float* vio = (float*)(wsb + OFF_VIO);

    const char* zr = zb + (t & 1) * ZBUF_B;
    char* zw = zb + ((t + 1) & 1) * ZBUF_B;

    // LI readout update for step t-1 (blocks 0-1 cover all 1024 (b,o) cells)
    const int g = blk * NTHR + tid;
    if (t > 0 && g < NB * NO) {
        const float* pr = pio + ((t - 1) & 1) * PIOHALF;
        const int b = g >> 2, o = g & 3;
        float s = 0.0f;
        #pragma unroll
        for (int jj = 0; jj < 64; ++jj) s += pr[b * 256 + jj * 4 + o];
        float vo = vio[g], io = vio[1024 + g], mx = vio[2048 + g];
        float von = __fadd_rn(vo, __fmul_rn(0.1f, __fsub_rn(io, vo)));  // old io
        io = __fadd_rn(__fmul_rn(io, 0.8f), s);
        vio[g] = von; vio[1024 + g] = io; vio[2048 + g] = fmaxf(mx, von);
    }

    // xs[t+1] -> next Z ext chunk (ht==8 blocks: 8 x 32 rows = all 256)
    if (ht == 8 && t + 1 < NT && tid < 32) {
        const int bg = b0 + tid;
        i32x4 xv = *(const i32x4*)(xsp + ((t + 1) * NB + bg) * 16);
        *(i32x4*)(zw + (((unsigned)(bg >> 4)) * KKT + 32u) * 1024u
                     + (unsigned)(bg & 15) * 16u) = xv;
    }
    if (tid < 128) w_out_lds[tid] = w_out[(tid >> 5) * NH + h0 + (tid & 31)];

    // ---- i8 MFMA GEMM: 8 waves stride K chunks by 8; 3 splits; 32b x 32h tile
    const int w = tid >> 6, lane = tid & 63;
    const unsigned lane16 = (unsigned)lane * 16u;

    i32x4 acc[2][2][3];   // [rb][hb][split]
    #pragma unroll
    for (int rb = 0; rb < 2; ++rb)
        #pragma unroll
        for (int hb = 0; hb < 2; ++hb)
            #pragma unroll
            for (int sp = 0; sp < 3; ++sp) acc[rb][hb][sp] = (i32x4){0, 0, 0, 0};

    const char* zA = zr + ((unsigned)(bt * 2) * KKT) * 1024u + lane16;   // rb stride KKT KB
    const char* wB = w3 + ((unsigned)(ht * 2) * KKT) * 1024u + lane16;   // hb stride KKT KB
    const unsigned rstr = (unsigned)KKT * 1024u;

    for (int kk = w; kk < KKT; kk += 8) {
        const unsigned o = (unsigned)kk * 1024u;
        i64x2 a0 = *(const i64x2*)(zA + o);
        i64x2 a1 = *(const i64x2*)(zA + rstr + o);
        #pragma unroll
        for (int sp = 0; sp < 3; ++sp) {
            #pragma unroll
            for (int hb = 0; hb < 2; ++hb) {
                i64x2 bf = *(const i64x2*)(wB + (unsigned)sp * SSTR
                                              + (unsigned)hb * rstr + o);
                acc[0][hb][sp] = __builtin_amdgcn_mfma_i32_16x16x32_i8(
                    a0[0], bf[0], acc[0][hb][sp], 0, 0, 0);
                acc[0][hb][sp] = __builtin_amdgcn_mfma_i32_16x16x32_i8(
                    a0[1], bf[1], acc[0][hb][sp], 0, 0, 0);
                acc[1][hb][sp] = __builtin_amdgcn_mfma_i32_16x16x32_i8(
                    a1[0], bf[0], acc[1][hb][sp], 0, 0, 0);
                acc[1][hb][sp] = __builtin_amdgcn_mfma_i32_16x16x32_i8(
                    a1[1], bf[1], acc[1][hb][sp], 0, 0, 0);
            }
        }
    }

    // combine splits -> f32, two-phase cross-wave reduce
    const int lk = lane >> 4, lh = lane & 15;
    const float inv0 = inv_scale[h0 + lh], inv1 = inv_scale[h0 + 16 + lh];
    float fc[2][2][4];
    #pragma unroll
    for (int rb = 0; rb < 2; ++rb)
        #pragma unroll
        for (int hb = 0; hb < 2; ++hb) {
            float invs = hb ? inv1 : inv0;
            #pragma unroll
            for (int r = 0; r < 4; ++r) {
                float f = fmaf((float)acc[rb][hb][2][r], 65536.0f,
                          fmaf((float)acc[rb][hb][1][r], 256.0f,
                               (float)acc[rb][hb][0][r]));
                fc[rb][hb][r] = f * invs;
            }
        }
    if (w >= 4) {
        #pragma unroll
        for (int rb = 0; rb < 2; ++rb)
            #pragma unroll
            for (int hb = 0; hb < 2; ++hb)
                #pragma unroll
                for (int r = 0; r < 4; ++r)
                    red[w - 4][(rb * 16 + lk * 4 + r) * 33 + hb * 16 + lh]
                        = fc[rb][hb][r];
    }
    __syncthreads();
    if (w < 4) {
        #pragma unroll
        for (int rb = 0; rb < 2; ++rb)
            #pragma unroll
            for (int hb = 0; hb < 2; ++hb)
                #pragma unroll
                for (int r = 0; r < 4; ++r) {
                    int ro = (rb * 16 + lk * 4 + r) * 33 + hb * 16 + lh;
                    red[w][ro] = fc[rb][hb][r] + red[w][ro];
                }
    }
    __syncthreads();

    // reduce 4 buffers + LIF update (2 elems/thread: 1024 = 32b x 32h)
    #pragma unroll
    for (int e = 0; e < 2; ++e) {
        int idx = e * NTHR + tid;
        int bl = idx >> 5, hl = idx & 31;
        int ro = bl * 33 + hl;
        float accv = ((red[0][ro] + red[1][ro]) + red[2][ro]) + red[3][ro];
        int gidx = (b0 + bl) * NH + h0 + hl;
        float vv = vst[gidx], ii = ist[gidx];
        float vd = __fadd_rn(vv, __fmul_rn(0.1f, __fsub_rn(ii, vv)));
        float zn = (__fsub_rn(vd, 1.0f) > 0.0f) ? 1.0f : 0.0f;
        vst[gidx] = (zn > 0.0f) ? 0.0f : vd;
        ist[gidx] = __fadd_rn(__fmul_rn(ii, 0.8f), accv);   // input current in GEMM ext
        z_s[ro] = zn;
    }
    __syncthreads();

    // spikes -> Z (this block owns chunk kk=ht>>1, q-pair ht&1) + readout partials
    if (tid < 256) {
        const int b = tid >> 3, seg = tid & 7;    // h = seg*4 .. +3
        const int bg = b0 + b;
        unsigned uw = 0;
        #pragma unroll
        for (int jj = 0; jj < 4; ++jj)
            uw |= (z_s[b * 33 + seg * 4 + jj] > 0.5f ? 1u : 0u) << (jj * 8);
        const unsigned q = (unsigned)((ht & 1) * 2 + (seg >> 2));
        *(unsigned*)(zw + (((unsigned)(bg >> 4)) * KKT + (unsigned)(ht >> 1)) * 1024u
                        + (q * 16u + (unsigned)(bg & 15)) * 16u + (unsigned)((seg & 3) * 4))
            = uw;
    }
    if (tid < 128) {
        const int b = tid >> 2, o = tid & 3;
        float s = 0.0f;
        #pragma unroll
        for (int h = 0; h < 32; ++h)
            s = fmaf(z_s[b * 33 + h], w_out_lds[o * 32 + h], s);
        float* pw = pio + (t & 1) * PIOHALF;
        pw[(b0 + b) * 256 + ht * 4 + o] = s;
    }
}

__global__ __launch_bounds__(256) void k_final(char* __restrict__ wsb,
                                               float* __restrict__ out) {
    const int g = blockIdx.x * 256 + threadIdx.x;   // 1024 threads (4 blocks!)
    if (g >= NB * NO) return;
    float* vio = (float*)(wsb + OFF_VIO);
    float vo = vio[g], io = vio[1024 + g], mx = vio[2048 + g];
    float von = __fadd_rn(vo, __fmul_rn(0.1f, __fsub_rn(io, vo)));
    mx = fmaxf(mx, von);

    float mm = fmaxf(mx, __shfl_xor(mx, 1, 64));
    mm = fmaxf(mm, __shfl_xor(mm, 2, 64));
    float e = expf(__fsub_rn(mx, mm));
    float es = e;
    es += __shfl_xor(es, 1, 64);
    es += __shfl_xor(es, 2, 64);
    out[g] = e / es;
}

extern "C" void kernel_launch(void* const* d_in, const int* in_sizes, int n_in,
                              void* d_out, int out_size, void* d_ws, size_t ws_size,
                              hipStream_t stream) {
    const float* x     = (const float*)d_in[0];
    const float* w_in  = (const float*)d_in[1];
    const float* w_rec = (const float*)d_in[2];
    const float* w_out = (const float*)d_in[3];
    float* out = (float*)d_out;
    char* wsb  = (char*)d_ws;

    k_scale<<<256, 512, 0, stream>>>(w_rec, w_in, wsb);
    k_pack<<<NH, 192, 0, stream>>>(w_rec, w_in, wsb);
    k_init<<<256, 256, 0, stream>>>(x, wsb);
    k_init2<<<1, 256, 0, stream>>>(wsb);
    for (int t = 0; t < NT; ++t)
        k_step<<<NBLK, NTHR, 0, stream>>>(w_out, wsb, t);
    k_final<<<4, 256, 0, stream>>>(wsb, out);
}

// Round 16
// 1462.895 us; speedup vs baseline: 1.7982x; 1.0007x over previous
//
#include <hip/hip_runtime.h>
#include <math.h>

#define NB 256
#define NH 2048
#define ND 8
#define NI 16
#define NT 128
#define NO 4
#define KKT 33           // K chunks of 64: 32 rec + 1 ext (w_in + zero pad) -> K = 2112
#define NTHR 512
#define NBLK 512

typedef __attribute__((ext_vector_type(4))) int i32x4;
typedef __attribute__((ext_vector_type(2))) long i64x2;

// ---- ws byte offsets ----
// W3: 3 i8 splits x [128 h16][33 kk][64 lane][16] (fragment-linear)
#define SSTR     (128u*KKT*1024u)                   // one split = 4,325,376 B
#define OFF_W3   0u
#define SZ_W3    (3u*SSTR)                          // 12,976,128
#define OFF_SC   (OFF_W3 + SZ_W3)                   // inv_scale f32[2048]
#define OFF_SCF  (OFF_SC + 8192u)                   // scale     f32[2048]
#define ZBUF_B   (16u*KKT*1024u)                    // 540,672 B per z buffer
#define OFF_ZB   (OFF_SCF + 8192u)                  // 2 x Z[16 b16][33 kk][64 lane][16] i8
#define SZ_ZB    (2u*ZBUF_B)
#define OFF_XS   (OFF_ZB + SZ_ZB)                   // [NT][NB][NI] i8 encoder spikes
#define SZ_XS    ((unsigned)NT*NB*NI)
#define OFF_V    (OFF_XS + SZ_XS)                   // [NB][NH] f32
#define SZ_V     ((unsigned)NB*NH*4u)
#define OFF_I    (OFF_V + SZ_V)
#define OFF_PIO  (OFF_I + SZ_V)                     // 2 x [256 b][64 ht][4 o] f32
#define PIOHALF  (NB*64*NO)                         // floats per half
#define OFF_VIO  (OFF_PIO + 2u*PIOHALF*4u)          // vo[1024], io[1024], mx[1024]

// per-row scales over [w_rec | w_in]: s = 22 - exp(rowmax) -> |w*2^s| < 2^23, 3 bytes
__global__ __launch_bounds__(512) void k_scale(const float* __restrict__ w_rec,
                                               const float* __restrict__ w_in,
                                               char* __restrict__ wsb) {
    const int gt = blockIdx.x * 512 + threadIdx.x;   // 256 blocks -> 2048 waves
    const int h = gt >> 6, lane = gt & 63;
    float m = 0.0f;
    for (int k = lane; k < NH; k += 64) m = fmaxf(m, fabsf(w_rec[h * NH + k]));
    if (lane < 16) m = fmaxf(m, fabsf(w_in[h * NI + lane]));
    #pragma unroll
    for (int d = 1; d < 64; d <<= 1) m = fmaxf(m, __shfl_xor(m, d, 64));
    if (lane == 0) {
        int e;
        frexpf(m, &e);           // m = f*2^e, f in [0.5,1)
        int s = 22 - e;
        ((float*)(wsb + OFF_SCF))[h] = ldexpf(1.0f, s);
        ((float*)(wsb + OFF_SC))[h]  = ldexpf(1.0f, -s);
    }
}

// quantize + split into 3 i8 planes, fragment-linear
__global__ __launch_bounds__(192) void k_pack(const float* __restrict__ w_rec,
                                              const float* __restrict__ w_in,
                                              char* __restrict__ wsb) {
    const int h = blockIdx.x, c = threadIdx.x;       // 2048 blocks, 132 chunks of 16 k
    if (c >= 132) return;
    const float scale = ((const float*)(wsb + OFF_SCF))[h];
    const int k0 = c * 16;
    const int kk = k0 >> 6, q = (k0 >> 4) & 3;
    unsigned pk[3][4] = {{0u,0u,0u,0u},{0u,0u,0u,0u},{0u,0u,0u,0u}};
    #pragma unroll
    for (int u = 0; u < 16; ++u) {
        int k = k0 + u;
        float wv = 0.0f;
        if (k < NH) wv = w_rec[h * NH + k];
        else if (k < NH + NI) wv = w_in[h * NI + (k - NH)];
        int wq = __float2int_rn(wv * scale);
        int b0_ = (wq << 24) >> 24;  int r = (wq - b0_) >> 8;
        int b1_ = (r << 24) >> 24;   int b2_ = (r - b1_) >> 8;
        int bs[3] = {b0_, b1_, b2_};
        #pragma unroll
        for (int sp = 0; sp < 3; ++sp)
            pk[sp][u >> 2] |= ((unsigned)(unsigned char)bs[sp]) << ((u & 3) * 8);
    }
    char* w3 = wsb + OFF_W3;
    unsigned base = (((unsigned)(h >> 4)) * KKT + (unsigned)kk) * 1024u
                  + ((unsigned)q * 16u + (unsigned)(h & 15)) * 16u;
    #pragma unroll
    for (int sp = 0; sp < 3; ++sp)
        *(i32x4*)(w3 + (unsigned)sp * SSTR + base) = *(const i32x4*)pk[sp];
}

__global__ __launch_bounds__(256) void k_init(const float* __restrict__ x,
                                              char* __restrict__ wsb) {
    const int g = blockIdx.x * 256 + threadIdx.x;   // 65536 threads
    unsigned* zb32 = (unsigned*)(wsb + OFF_ZB);     // 270,336 uints
    float* vst = (float*)(wsb + OFF_V);
    float* ist = (float*)(wsb + OFF_I);
    float* vio = (float*)(wsb + OFF_VIO);
    char* xsp = (char*)(wsb + OFF_XS);

    #pragma unroll
    for (int r = 0; r < 5; ++r) {
        unsigned off = (unsigned)g + (unsigned)r * 65536u;
        if (off < (SZ_ZB / 4u)) zb32[off] = 0u;
    }
    #pragma unroll
    for (int r = 0; r < 8; ++r) vst[g + r * 65536] = 0.0f;
    #pragma unroll
    for (int r = 0; r < 8; ++r) ist[g + r * 65536] = 0.0f;
    if (g < 3072) vio[g] = (g < 2048) ? 0.0f : -3.0e38f;

    if (g < NB * NI) {   // encoder cell (b, ci)
        const int b = g >> 4, ci = g & 15;
        float xv = x[b * ND + (ci & 7)];
        float c = (ci < 8) ? __fmul_rn(50.0f, xv) : __fmul_rn(-50.0f, xv);
        c = fmaxf(c, 0.0f);
        float ev = 0.0f;
        for (int t = 0; t < NT; ++t) {
            ev = __fadd_rn(ev, __fmul_rn(0.1f, __fsub_rn(c, ev)));
            float z = (__fsub_rn(ev, 1.0f) > 0.0f) ? 1.0f : 0.0f;
            xsp[t * (NB * NI) + g] = (z > 0.0f) ? (char)1 : (char)0;
            ev = (z > 0.0f) ? 0.0f : ev;
        }
    }
}

// xs[0] -> Z buffer 0 ext chunk (kk=32, q=0)
__global__ __launch_bounds__(256) void k_init2(char* __restrict__ wsb) {
    const int b = threadIdx.x;                       // 256 threads
    char* zb0 = wsb + OFF_ZB;
    const char* xsp = wsb + OFF_XS;
    i32x4 xv = *(const i32x4*)(xsp + b * 16);
    *(i32x4*)(zb0 + (((unsigned)(b >> 4)) * KKT + 32u) * 1024u
                  + (unsigned)(b & 15) * 16u) = xv;
}

// 512 blocks x 512 thr (2 blocks/CU, 16 waves/CU): tile 32b x 32h, waves stride K by 8
__global__ __launch_bounds__(NTHR, 4) void k_step(const float* __restrict__ w_out,
                                                  char* __restrict__ wsb, int t) {
    __shared__ float red[4][32 * 33];    // 4 k-partial buffers (two-phase reduce)
    __shared__ float z_s[32 * 33];
    __shared__ float w_out_lds[128];     // LDS total = 21,632 B

    const int tid = threadIdx.x;
    const int blk = blockIdx.x;
    const int xcd = blk & 7, j = blk >> 3;
    const int ht = xcd * 8 + (j & 7);    // 0..63 (h-tile, XCD-local weights)
    const int bt = j >> 3;               // 0..7
    const int b0 = bt * 32, h0 = ht * 32;

    const char* w3 = wsb + OFF_W3;
    const float* inv_scale = (const float*)(wsb + OFF_SC);
    char* zb = wsb + OFF_ZB;
    const char* xsp = wsb + OFF_XS;
    float* vst = (float*)(wsb + OFF_V);
    float* ist = (float*)(wsb + OFF_I);
    float* pio = (float*)(wsb + OFF_PIO);
    float* vio = (float*)(wsb + OFF_VIO);

    const char* zr = zb + (t & 1) * ZBUF_B;
    char* zw = zb + ((t + 1) & 1) * ZBUF_B;

    // LI readout update for step t-1 (blocks 0-1 cover all 1024 (b,o) cells)
    const int g = blk * NTHR + tid;
    if (t > 0 && g < NB * NO) {
        const float* pr = pio + ((t - 1) & 1) * PIOHALF;
        const int b = g >> 2, o = g & 3;
        float s = 0.0f;
        #pragma unroll
        for (int jj = 0; jj < 64; ++jj) s += pr[b * 256 + jj * 4 + o];
        float vo = vio[g], io = vio[1024 + g], mx = vio[2048 + g];
        float von = __fadd_rn(vo, __fmul_rn(0.1f, __fsub_rn(io, vo)));  // old io
        io = __fadd_rn(__fmul_rn(io, 0.8f), s);
        vio[g] = von; vio[1024 + g] = io; vio[2048 + g] = fmaxf(mx, von);
    }

    // xs[t+1] -> next Z ext chunk (ht==8 blocks: 8 x 32 rows = all 256)
    if (ht == 8 && t + 1 < NT && tid < 32) {
        const int bg = b0 + tid;
        i32x4 xv = *(const i32x4*)(xsp + ((t + 1) * NB + bg) * 16);
        *(i32x4*)(zw + (((unsigned)(bg >> 4)) * KKT + 32u) * 1024u
                     + (unsigned)(bg & 15) * 16u) = xv;
    }
    if (tid < 128) w_out_lds[tid] = w_out[(tid >> 5) * NH + h0 + (tid & 31)];

    // ---- i8 MFMA GEMM: 8 waves stride K chunks by 8; 3 splits; 32b x 32h tile
    const int w = tid >> 6, lane = tid & 63;
    const unsigned lane16 = (unsigned)lane * 16u;

    i32x4 acc[2][2][3];   // [rb][hb][split]
    #pragma unroll
    for (int rb = 0; rb < 2; ++rb)
        #pragma unroll
        for (int hb = 0; hb < 2; ++hb)
            #pragma unroll
            for (int sp = 0; sp < 3; ++sp) acc[rb][hb][sp] = (i32x4){0, 0, 0, 0};

    const char* zA = zr + ((unsigned)(bt * 2) * KKT) * 1024u + lane16;   // rb stride KKT KB
    const char* wB = w3 + ((unsigned)(ht * 2) * KKT) * 1024u + lane16;   // hb stride KKT KB
    const unsigned rstr = (unsigned)KKT * 1024u;

    for (int kk = w; kk < KKT; kk += 8) {
        const unsigned o = (unsigned)kk * 1024u;
        i64x2 a0 = *(const i64x2*)(zA + o);
        i64x2 a1 = *(const i64x2*)(zA + rstr + o);
        #pragma unroll
        for (int sp = 0; sp < 3; ++sp) {
            #pragma unroll
            for (int hb = 0; hb < 2; ++hb) {
                i64x2 bf = *(const i64x2*)(wB + (unsigned)sp * SSTR
                                              + (unsigned)hb * rstr + o);
                acc[0][hb][sp] = __builtin_amdgcn_mfma_i32_16x16x32_i8(
                    a0[0], bf[0], acc[0][hb][sp], 0, 0, 0);
                acc[0][hb][sp] = __builtin_amdgcn_mfma_i32_16x16x32_i8(
                    a0[1], bf[1], acc[0][hb][sp], 0, 0, 0);
                acc[1][hb][sp] = __builtin_amdgcn_mfma_i32_16x16x32_i8(
                    a1[0], bf[0], acc[1][hb][sp], 0, 0, 0);
                acc[1][hb][sp] = __builtin_amdgcn_mfma_i32_16x16x32_i8(
                    a1[1], bf[1], acc[1][hb][sp], 0, 0, 0);
            }
        }
    }

    // combine splits -> f32, two-phase cross-wave reduce
    const int lk = lane >> 4, lh = lane & 15;
    const float inv0 = inv_scale[h0 + lh], inv1 = inv_scale[h0 + 16 + lh];
    float fc[2][2][4];
    #pragma unroll
    for (int rb = 0; rb < 2; ++rb)
        #pragma unroll
        for (int hb = 0; hb < 2; ++hb) {
            float invs = hb ? inv1 : inv0;
            #pragma unroll
            for (int r = 0; r < 4; ++r) {
                float f = fmaf((float)acc[rb][hb][2][r], 65536.0f,
                          fmaf((float)acc[rb][hb][1][r], 256.0f,
                               (float)acc[rb][hb][0][r]));
                fc[rb][hb][r] = f * invs;
            }
        }
    if (w >= 4) {
        #pragma unroll
        for (int rb = 0; rb < 2; ++rb)
            #pragma unroll
            for (int hb = 0; hb < 2; ++hb)
                #pragma unroll
                for (int r = 0; r < 4; ++r)
                    red[w - 4][(rb * 16 + lk * 4 + r) * 33 + hb * 16 + lh]
                        = fc[rb][hb][r];
    }
    __syncthreads();
    if (w < 4) {
        #pragma unroll
        for (int rb = 0; rb < 2; ++rb)
            #pragma unroll
            for (int hb = 0; hb < 2; ++hb)
                #pragma unroll
                for (int r = 0; r < 4; ++r) {
                    int ro = (rb * 16 + lk * 4 + r) * 33 + hb * 16 + lh;
                    red[w][ro] = fc[rb][hb][r] + red[w][ro];
                }
    }
    __syncthreads();

    // reduce 4 buffers + LIF update (2 elems/thread: 1024 = 32b x 32h)
    #pragma unroll
    for (int e = 0; e < 2; ++e) {
        int idx = e * NTHR + tid;
        int bl = idx >> 5, hl = idx & 31;
        int ro = bl * 33 + hl;
        float accv = ((red[0][ro] + red[1][ro]) + red[2][ro]) + red[3][ro];
        int gidx = (b0 + bl) * NH + h0 + hl;
        float vv = vst[gidx], ii = ist[gidx];
        float vd = __fadd_rn(vv, __fmul_rn(0.1f, __fsub_rn(ii, vv)));
        float zn = (__fsub_rn(vd, 1.0f) > 0.0f) ? 1.0f : 0.0f;
        vst[gidx] = (zn > 0.0f) ? 0.0f : vd;
        ist[gidx] = __fadd_rn(__fmul_rn(ii, 0.8f), accv);   // input current in GEMM ext
        z_s[ro] = zn;
    }
    __syncthreads();

    // spikes -> Z (this block owns chunk kk=ht>>1, q-pair ht&1) + readout partials
    if (tid < 256) {
        const int b = tid >> 3, seg = tid & 7;    // h = seg*4 .. +3
        const int bg = b0 + b;
        unsigned uw = 0;
        #pragma unroll
        for (int jj = 0; jj < 4; ++jj)
            uw |= (z_s[b * 33 + seg * 4 + jj] > 0.5f ? 1u : 0u) << (jj * 8);
        const unsigned q = (unsigned)((ht & 1) * 2 + (seg >> 2));
        *(unsigned*)(zw + (((unsigned)(bg >> 4)) * KKT + (unsigned)(ht >> 1)) * 1024u
                        + (q * 16u + (unsigned)(bg & 15)) * 16u + (unsigned)((seg & 3) * 4))
            = uw;
    }
    if (tid < 128) {
        const int b = tid >> 2, o = tid & 3;
        float s = 0.0f;
        #pragma unroll
        for (int h = 0; h < 32; ++h)
            s = fmaf(z_s[b * 33 + h], w_out_lds[o * 32 + h], s);
        float* pw = pio + (t & 1) * PIOHALF;
        pw[(b0 + b) * 256 + ht * 4 + o] = s;
    }
}

__global__ __launch_bounds__(256) void k_final(char* __restrict__ wsb,
                                               float* __restrict__ out) {
    const int g = blockIdx.x * 256 + threadIdx.x;   // 1024 threads (4 blocks!)
    if (g >= NB * NO) return;
    float* vio = (float*)(wsb + OFF_VIO);
    float vo = vio[g], io = vio[1024 + g], mx = vio[2048 + g];
    float von = __fadd_rn(vo, __fmul_rn(0.1f, __fsub_rn(io, vo)));
    mx = fmaxf(mx, von);

    float mm = fmaxf(mx, __shfl_xor(mx, 1, 64));
    mm = fmaxf(mm, __shfl_xor(mm, 2, 64));
    float e = expf(__fsub_rn(mx, mm));
    float es = e;
    es += __shfl_xor(es, 1, 64);
    es += __shfl_xor(es, 2, 64);
    out[g] = e / es;
}

extern "C" void kernel_launch(void* const* d_in, const int* in_sizes, int n_in,
                              void* d_out, int out_size, void* d_ws, size_t ws_size,
                              hipStream_t stream) {
    const float* x     = (const float*)d_in[0];
    const float* w_in  = (const float*)d_in[1];
    const float* w_rec = (const float*)d_in[2];
    const float* w_out = (const float*)d_in[3];
    float* out = (float*)d_out;
    char* wsb  = (char*)d_ws;

    k_scale<<<256, 512, 0, stream>>>(w_rec, w_in, wsb);
    k_pack<<<NH, 192, 0, stream>>>(w_rec, w_in, wsb);
    k_init<<<256, 256, 0, stream>>>(x, wsb);
    k_init2<<<1, 256, 0, stream>>>(wsb);
    for (int t = 0; t < NT; ++t)
        k_step<<<NBLK, NTHR, 0, stream>>>(w_out, wsb, t);
    k_final<<<4, 256, 0, stream>>>(wsb, out);
}